// Round 10
// baseline (213.560 us; speedup 1.0000x reference)
//
#include <hip/hip_runtime.h>
#include <math.h>

#define NN 40000
#define NE 640000
#define D 128
#define NH 4
#define NC 32
#define NEG 0.2f

#define NBKT 625      // buckets of 64 dst-nodes
#define NBIN 500      // binning blocks (1280 edges each); lambda=2.05/segment
#define SEGC 16       // records per (bucket,bin) segment = 64 B full line

typedef __attribute__((ext_vector_type(8))) short bf16x8;
typedef __attribute__((ext_vector_type(4))) float f32x4;

__device__ __forceinline__ unsigned pack_bf16(float a, float b) {
  unsigned ua = __float_as_uint(a), ub = __float_as_uint(b);
  ua = (ua + 0x7FFFu + ((ua >> 16) & 1u)) >> 16;
  ub = (ub + 0x7FFFu + ((ub >> 16) & 1u)) & 0xFFFF0000u;
  return ub | ua;
}

__device__ __forceinline__ bf16x8 to_bf16x8(float4 a, float4 b) {
  union { bf16x8 v; unsigned u[4]; } r;
  r.u[0] = pack_bf16(a.x, a.y);
  r.u[1] = pack_bf16(a.z, a.w);
  r.u[2] = pack_bf16(b.x, b.y);
  r.u[3] = pack_bf16(b.z, b.w);
  return r.v;
}

__device__ __forceinline__ float4 f4add(float4 a, float4 b) {
  return make_float4(a.x + b.x, a.y + b.y, a.z + b.z, a.w + b.w);
}

// ======= k_pb: b<500 -> LDS-staged edge binning (R7 verbatim, verified);
//         b>=500 -> weight tables (17 blocks). =======
__global__ __launch_bounds__(256) void k_pb(
    const int* __restrict__ ei, const int* __restrict__ etype,
    unsigned* __restrict__ binbuf,
    const float* __restrict__ Wq, const float* __restrict__ Wk,
    const float* __restrict__ Wv,
    const float* __restrict__ att_i, const float* __restrict__ att_j,
    const float* __restrict__ eemb,
    float* __restrict__ ev, float* __restrict__ a_et,
    unsigned* __restrict__ Wvh) {
  __shared__ unsigned smem[10640];  // bin: slab[10000] + hist[625] ; tables: sm[1024]f
  int b = blockIdx.x, t = threadIdx.x;

  if (b < NBIN) {
    unsigned* lbuf = smem;             // 625 segments x 16
    int* hist = (int*)(smem + 10000);  // 625
    for (int j = t; j < NBKT; j += 256) hist[j] = 0;
    __syncthreads();
    int e0 = b * 1280;
#pragma unroll
    for (int k = 0; k < 5; ++k) {
      int e = e0 + k * 256 + t;
      int src = ei[e];
      int dst = ei[NE + e];
      int et  = etype[e];
      int bk = dst >> 6;
      int r = atomicAdd(&hist[bk], 1);
      if (r < SEGC)
        lbuf[bk * SEGC + r] =
            (unsigned)src | ((unsigned)et << 16) | ((unsigned)(dst & 63) << 19);
    }
    __syncthreads();
    for (int j = t; j < NBKT; j += 256) {
      unsigned c = (unsigned)min(hist[j], SEGC);
      unsigned s0 = (c == 0) ? 0u : (lbuf[j * SEGC] & 0x01FFFFFFu);
      lbuf[j * SEGC] = s0 | (c << 27);
    }
    __syncthreads();
    for (int j = t; j < NBKT; j += 256) {
      const uint4* __restrict__ s4 = (const uint4*)(lbuf + j * SEGC);
      uint4* __restrict__ d4 = (uint4*)(binbuf + ((size_t)j * NBIN + b) * SEGC);
      d4[0] = s4[0]; d4[1] = s4[1]; d4[2] = s4[2]; d4[3] = s4[3];
    }
    return;
  }

  // ---------------- tables ----------------
  float* sm = (float*)smem;
  int tb = b - NBIN;
  if (tb == 0) {
    for (int j = t; j < 1024; j += 256) {
      int isq = (j < 512);
      int h = (j >> 7) & 3, d = j & 127;
      const float* __restrict__ Wm = isq ? Wq : Wk;
      const float* __restrict__ am = isq ? att_i : att_j;
      float s = 0.f;
#pragma unroll
      for (int c = 0; c < NC; ++c) s = fmaf(am[h * NC + c], Wm[(h * NC + c) * D + d], s);
      sm[j] = s;
    }
    __syncthreads();
    for (int j = t; j < 1024; j += 256) {
      int r = j >> 6;
      int c2 = (j & 63) * 2;
      float a = 0.f, bb = 0.f;
      if (r < 8) { a = sm[r * 128 + c2]; bb = sm[r * 128 + c2 + 1]; }
      Wvh[(128 + r) * 64 + (j & 63)] = pack_bf16(a, bb);
    }
    if (t < 32) {  // a_et[ty][h] = wk_eff[h] . eemb[ty]
      int ty = t >> 2, hh = t & 3;
      const float* wrow = sm + 512 + hh * 128;
      const float* __restrict__ emb = eemb + ty * D;
      float s = 0.f;
#pragma unroll 8
      for (int d = 0; d < D; ++d) s = fmaf(wrow[d], emb[d], s);
      a_et[t] = s;
    }
  } else if (tb <= 8) {
    int ty = tb - 1;
    if (t < 128) sm[t] = eemb[ty * D + t];
    __syncthreads();
    if (t < 128) {
      const float4* __restrict__ wr = (const float4*)(Wv + (size_t)t * D);
      const float4* __restrict__ er = (const float4*)sm;
      float s = 0.f;
#pragma unroll
      for (int k = 0; k < 32; ++k) {
        float4 ww = wr[k], ee = er[k];
        s = fmaf(ww.x, ee.x, s); s = fmaf(ww.y, ee.y, s);
        s = fmaf(ww.z, ee.z, s); s = fmaf(ww.w, ee.w, s);
      }
      ev[ty * D + t] = s;
    }
  } else {
    int j0 = (tb - 9) * 1024;
    for (int j = j0 + t; j < j0 + 1024; j += 256)
      Wvh[j] = pack_bf16(Wv[2 * j], Wv[2 * j + 1]);
  }
}

// ====== MFMA xv (625 blocks) — verbatim ======
__global__ __launch_bounds__(256) void k_xv(
    const float* __restrict__ x, const int* __restrict__ node_type,
    const float* __restrict__ nemb, const unsigned* __restrict__ Wvh,
    unsigned* __restrict__ xvh, float* __restrict__ aq, float* __restrict__ ak) {
  int bb = blockIdx.x, t = threadIdx.x;
  int w = t >> 6, l = t & 63;
  int quad = l >> 4, col = l & 15;
  int n0w = bb * 64 + w * 16;  // 40000 = 625*64
  int node = n0w + col;
  int ntA = node_type[node];
  const float4* __restrict__ xr = (const float4*)(x + (size_t)node * D);
  const float4* __restrict__ nr = (const float4*)(nemb + (size_t)ntA * D);
  bf16x8 afr[4];
#pragma unroll
  for (int s = 0; s < 4; ++s) {
    const float4* p = xr + s * 8 + quad * 2;
    const float4* q4 = nr + s * 8 + quad * 2;
    afr[s] = to_bf16x8(f4add(p[0], q4[0]), f4add(p[1], q4[1]));
  }
  f32x4 acc[9];
#pragma unroll
  for (int ct = 0; ct < 9; ++ct) acc[ct] = (f32x4){0.f, 0.f, 0.f, 0.f};
#pragma unroll
  for (int ct = 0; ct < 9; ++ct) {
    const unsigned* __restrict__ brow = Wvh + (size_t)(ct * 16 + col) * 64;
#pragma unroll
    for (int s = 0; s < 4; ++s) {
      bf16x8 bfr = *(const bf16x8*)(brow + s * 16 + quad * 4);
      acc[ct] = __builtin_amdgcn_mfma_f32_16x16x32_bf16(afr[s], bfr, acc[ct], 0, 0, 0);
    }
  }
  int nodes[4];
#pragma unroll
  for (int r = 0; r < 4; ++r) nodes[r] = n0w + quad * 4 + r;
#pragma unroll
  for (int ct = 0; ct < 8; ++ct) {
#pragma unroll
    for (int r = 0; r < 4; ++r) {
      float val = acc[ct][r];
      float pv = __shfl_xor(val, 1);
      if (!(col & 1)) {
        xvh[nodes[r] * 64 + ct * 8 + (col >> 1)] = pack_bf16(val, pv);
      }
    }
  }
  if (col < 4) {
#pragma unroll
    for (int r = 0; r < 4; ++r) aq[nodes[r] * NH + col] = acc[8][r];
  } else if (col < 8) {
#pragma unroll
    for (int r = 0; r < 4; ++r) ak[nodes[r] * NH + (col - 4)] = acc[8][r];
  }
}

// ====== k_gb: channel-split gather. 1256 blocks x 512 threads.
//        bid -> x=bid&7: half=(x>>2) (XCD-group pinned under bid%8 round-robin),
//        bucket=(bid>>3)*4+(x&3). Block handles 64 nodes x 64 channels
//        (heads {2*half, 2*half+1}). Per node: 16 item-stripes x 4 ch-groups.
//        CSR build identical R7 (full bucket; binbuf read by both halves,
//        L3-resident). ======
__global__ __launch_bounds__(512) void k_gb(
    const unsigned* __restrict__ binbuf,
    const float* __restrict__ aq, const float* __restrict__ ak,
    const float* __restrict__ a_et, const unsigned* __restrict__ xvh,
    const float* __restrict__ ev, const float* __restrict__ bias,
    float* __restrict__ out) {
  __shared__ int lcnt[64];
  __shared__ unsigned csr[4096];
  int bid = blockIdx.x, t = threadIdx.x;
  int xx = bid & 7;
  int half = xx >> 2;
  int b = (bid >> 3) * 4 + (xx & 3);  // bucket
  if (b >= NBKT) return;
  if (t < 64) lcnt[t] = 0;
  __syncthreads();
  if (t < NBIN) {
    const unsigned* __restrict__ sp = binbuf + ((size_t)b * NBIN + t) * SEGC;
    uint4 a0 = *(const uint4*)sp;
    uint4 a1 = *(const uint4*)(sp + 4);
    uint4 a2 = *(const uint4*)(sp + 8);
    uint4 a3 = *(const uint4*)(sp + 12);
    unsigned rr[16] = {a0.x, a0.y, a0.z, a0.w, a1.x, a1.y, a1.z, a1.w,
                       a2.x, a2.y, a2.z, a2.w, a3.x, a3.y, a3.z, a3.w};
    int cnt = (int)(rr[0] >> 27);
    rr[0] &= 0x01FFFFFFu;
#pragma unroll
    for (int j = 0; j < SEGC; ++j) {
      if (j < cnt) {
        unsigned rec = rr[j];
        int loc = (int)(rec >> 19) & 63;
        int r = atomicAdd(&lcnt[loc], 1);
        if (r < 63) csr[(loc << 6) + r] = rec & 0x7FFFFu;  // src | et<<16
      }
    }
  }
  __syncthreads();
  int w = t >> 6, l = t & 63;
  int gp = l >> 2, qp = l & 3;        // 16 item stripes x 4 ch-groups (16 ch)
  int h = 2 * half + (qp >> 1);       // global head
  int gt = gp & 7;                    // type index for ev correction (gp<8 only)
  const uint4* __restrict__ xv4 = (const uint4*)xvh;  // row = 16 uint4
  const float4* __restrict__ ep = (const float4*)(ev + gt * D + 64 * half + 16 * qp);
  float4 ea0 = ep[0], ea1 = ep[1], ea2 = ep[2], ea3 = ep[3];
  int cbase = half * 8 + 2 * qp;      // uint4 chunk index within row
#pragma unroll 1
  for (int j4 = 0; j4 < 8; ++j4) {
    int loc = (w << 3) + j4;
    int n = (b << 6) + loc;
    float aqh = aq[n * NH + h];
    int deg = min(lcnt[loc], 63);
    int m = deg + 1;  // + virtual self-loop at item index deg
    float acc[16];
#pragma unroll
    for (int k = 0; k < 16; ++k) acc[k] = 0.f;
    float ps[8];
#pragma unroll
    for (int k = 0; k < 8; ++k) ps[k] = 0.f;
    int iters = (m + 15) >> 4;
    int i = gp;
    bool val = (i < m);
    unsigned rec = (val && i < deg) ? csr[(loc << 6) + i] : (unsigned)n;
    int src = (int)(rec & 0xFFFFu), etc = (int)(rec >> 16);
    float sA = ak[src * NH + h] + a_et[etc * NH + h];
    uint4 vb0 = xv4[src * 16 + cbase];
    uint4 vb1 = xv4[src * 16 + cbase + 1];
    for (int it = 0; it < iters; ++it) {
      int i2 = i + 16;
      bool v2 = (i2 < m);
      float sAn = 0.f; int etn = 0;
      uint4 vb0n = make_uint4(0, 0, 0, 0), vb1n = make_uint4(0, 0, 0, 0);
      if (it + 1 < iters) {
        unsigned rec2 = (v2 && i2 < deg) ? csr[(loc << 6) + i2] : (unsigned)n;
        int s2 = (int)(rec2 & 0xFFFFu);
        etn = (int)(rec2 >> 16);
        sAn = ak[s2 * NH + h] + a_et[etn * NH + h];
        vb0n = xv4[s2 * 16 + cbase];
        vb1n = xv4[s2 * 16 + cbase + 1];
      }
      float s = aqh + sA;
      s = (s > 0.f) ? s : NEG * s;
      float p = val ? __expf(s) : 0.f;
#pragma unroll
      for (int tt = 0; tt < 8; ++tt) ps[tt] += (etc == tt) ? p : 0.f;
      float f[16];
      f[0]  = __uint_as_float(vb0.x << 16); f[1]  = __uint_as_float(vb0.x & 0xFFFF0000u);
      f[2]  = __uint_as_float(vb0.y << 16); f[3]  = __uint_as_float(vb0.y & 0xFFFF0000u);
      f[4]  = __uint_as_float(vb0.z << 16); f[5]  = __uint_as_float(vb0.z & 0xFFFF0000u);
      f[6]  = __uint_as_float(vb0.w << 16); f[7]  = __uint_as_float(vb0.w & 0xFFFF0000u);
      f[8]  = __uint_as_float(vb1.x << 16); f[9]  = __uint_as_float(vb1.x & 0xFFFF0000u);
      f[10] = __uint_as_float(vb1.y << 16); f[11] = __uint_as_float(vb1.y & 0xFFFF0000u);
      f[12] = __uint_as_float(vb1.z << 16); f[13] = __uint_as_float(vb1.z & 0xFFFF0000u);
      f[14] = __uint_as_float(vb1.w << 16); f[15] = __uint_as_float(vb1.w & 0xFFFF0000u);
#pragma unroll
      for (int k = 0; k < 16; ++k) acc[k] = fmaf(p, f[k], acc[k]);
      i = i2; val = v2; sA = sAn; etc = etn; vb0 = vb0n; vb1 = vb1n;
    }
    // reduce ps over the 16 item-stripes (lane bits 2..5)
#pragma unroll
    for (int tt = 0; tt < 8; ++tt) {
      ps[tt] += __shfl_xor(ps[tt], 4);
      ps[tt] += __shfl_xor(ps[tt], 8);
      ps[tt] += __shfl_xor(ps[tt], 16);
      ps[tt] += __shfl_xor(ps[tt], 32);
    }
    float dsum = ((ps[0] + ps[1]) + (ps[2] + ps[3])) + ((ps[4] + ps[5]) + (ps[6] + ps[7]));
    float psg = ps[0];
#pragma unroll
    for (int tt = 1; tt < 8; ++tt) psg = (gt == tt) ? ps[tt] : psg;
    psg = (gp < 8) ? psg : 0.f;  // stripes 8..15 apply no type correction
    acc[0]  = fmaf(psg, ea0.x, acc[0]);
    acc[1]  = fmaf(psg, ea0.y, acc[1]);
    acc[2]  = fmaf(psg, ea0.z, acc[2]);
    acc[3]  = fmaf(psg, ea0.w, acc[3]);
    acc[4]  = fmaf(psg, ea1.x, acc[4]);
    acc[5]  = fmaf(psg, ea1.y, acc[5]);
    acc[6]  = fmaf(psg, ea1.z, acc[6]);
    acc[7]  = fmaf(psg, ea1.w, acc[7]);
    acc[8]  = fmaf(psg, ea2.x, acc[8]);
    acc[9]  = fmaf(psg, ea2.y, acc[9]);
    acc[10] = fmaf(psg, ea2.z, acc[10]);
    acc[11] = fmaf(psg, ea2.w, acc[11]);
    acc[12] = fmaf(psg, ea3.x, acc[12]);
    acc[13] = fmaf(psg, ea3.y, acc[13]);
    acc[14] = fmaf(psg, ea3.z, acc[14]);
    acc[15] = fmaf(psg, ea3.w, acc[15]);
#pragma unroll
    for (int k = 0; k < 16; ++k) {
      acc[k] += __shfl_xor(acc[k], 4);
      acc[k] += __shfl_xor(acc[k], 8);
      acc[k] += __shfl_xor(acc[k], 16);
      acc[k] += __shfl_xor(acc[k], 32);
    }
    if (gp == 0) {
      float inv = 1.f / (dsum + 1e-16f);
      const float4* __restrict__ b4 = (const float4*)(bias + 64 * half + 16 * qp);
      float4* __restrict__ op = (float4*)(out + (size_t)n * D + 64 * half + 16 * qp);
#pragma unroll
      for (int k4 = 0; k4 < 4; ++k4) {
        float4 bb = b4[k4];
        op[k4] = make_float4(acc[4 * k4 + 0] * inv + bb.x,
                             acc[4 * k4 + 1] * inv + bb.y,
                             acc[4 * k4 + 2] * inv + bb.z,
                             acc[4 * k4 + 3] * inv + bb.w);
      }
    }
  }
}

extern "C" void kernel_launch(void* const* d_in, const int* in_sizes, int n_in,
                              void* d_out, int out_size, void* d_ws, size_t ws_size,
                              hipStream_t stream) {
  const float* x      = (const float*)d_in[0];
  const int*   ei     = (const int*)d_in[1];
  const int*   ntype  = (const int*)d_in[2];
  const int*   etype  = (const int*)d_in[3];
  const float* Wq     = (const float*)d_in[4];
  const float* Wk     = (const float*)d_in[5];
  const float* Wv     = (const float*)d_in[6];
  const float* att_i  = (const float*)d_in[7];
  const float* att_j  = (const float*)d_in[8];
  const float* bias   = (const float*)d_in[9];
  const float* nemb   = (const float*)d_in[10];
  const float* eemb   = (const float*)d_in[11];
  float* out = (float*)d_out;

  float* ws     = (float*)d_ws;
  unsigned* xvh = (unsigned*)ws;               // NN*64 uints (bf16 pairs)
  float* aq     = ws + (size_t)NN * 64;        // NN*4
  float* ak     = aq + NN * NH;                // NN*4
  float* ev     = ak + NN * NH;                // 1024
  float* a_et   = ev + 1024;                   // 32
  unsigned* Wvh = (unsigned*)(a_et + 32);      // 144*64 = 9216 uints
  unsigned* binbuf = (unsigned*)(Wvh + 9216);  // NBKT*NBIN*SEGC = 5M uints = 20MB, 64B-aligned

  k_pb<<<dim3(NBIN + 17), dim3(256), 0, stream>>>(ei, etype, binbuf,
                                                  Wq, Wk, Wv, att_i, att_j, eemb,
                                                  ev, a_et, Wvh);
  k_xv<<<dim3(625), dim3(256), 0, stream>>>(x, ntype, nemb, Wvh, xvh, aq, ak);
  k_gb<<<dim3(157 * 8), dim3(512), 0, stream>>>(binbuf, aq, ak, a_et,
                                                xvh, ev, bias, out);
}

// Round 11
// 171.693 us; speedup vs baseline: 1.2439x; 1.2439x over previous
//
#include <hip/hip_runtime.h>
#include <math.h>

#define NN 40000
#define NE 640000
#define D 128
#define NH 4
#define NC 32
#define NEG 0.2f

#define NBKT 625      // buckets of 64 dst-nodes
#define NBIN 500      // binning blocks (1280 edges each); lambda=2.05/segment
#define SEGC 16       // records per (bucket,bin) segment = 64 B full line

typedef __attribute__((ext_vector_type(8))) short bf16x8;
typedef __attribute__((ext_vector_type(4))) float f32x4;

__device__ __forceinline__ unsigned pack_bf16(float a, float b) {
  unsigned ua = __float_as_uint(a), ub = __float_as_uint(b);
  ua = (ua + 0x7FFFu + ((ua >> 16) & 1u)) >> 16;
  ub = (ub + 0x7FFFu + ((ub >> 16) & 1u)) & 0xFFFF0000u;
  return ub | ua;
}

__device__ __forceinline__ bf16x8 to_bf16x8(float4 a, float4 b) {
  union { bf16x8 v; unsigned u[4]; } r;
  r.u[0] = pack_bf16(a.x, a.y);
  r.u[1] = pack_bf16(a.z, a.w);
  r.u[2] = pack_bf16(b.x, b.y);
  r.u[3] = pack_bf16(b.z, b.w);
  return r.v;
}

__device__ __forceinline__ float4 f4add(float4 a, float4 b) {
  return make_float4(a.x + b.x, a.y + b.y, a.z + b.z, a.w + b.w);
}

// ======= k_pb: b<500 -> LDS-staged edge binning (verified R7);
//         b>=500 -> weight tables (17 blocks). =======
__global__ __launch_bounds__(256) void k_pb(
    const int* __restrict__ ei, const int* __restrict__ etype,
    unsigned* __restrict__ binbuf,
    const float* __restrict__ Wq, const float* __restrict__ Wk,
    const float* __restrict__ Wv,
    const float* __restrict__ att_i, const float* __restrict__ att_j,
    const float* __restrict__ eemb,
    float* __restrict__ ev, float* __restrict__ a_et,
    unsigned* __restrict__ Wvh) {
  __shared__ unsigned smem[10640];  // bin: slab[10000] + hist[625] ; tables: sm[1024]f
  int b = blockIdx.x, t = threadIdx.x;

  if (b < NBIN) {
    unsigned* lbuf = smem;             // 625 segments x 16
    int* hist = (int*)(smem + 10000);  // 625
    for (int j = t; j < NBKT; j += 256) hist[j] = 0;
    __syncthreads();
    int e0 = b * 1280;
#pragma unroll
    for (int k = 0; k < 5; ++k) {
      int e = e0 + k * 256 + t;
      int src = ei[e];
      int dst = ei[NE + e];
      int et  = etype[e];
      int bk = dst >> 6;
      int r = atomicAdd(&hist[bk], 1);
      if (r < SEGC)
        lbuf[bk * SEGC + r] =
            (unsigned)src | ((unsigned)et << 16) | ((unsigned)(dst & 63) << 19);
    }
    __syncthreads();
    for (int j = t; j < NBKT; j += 256) {
      unsigned c = (unsigned)min(hist[j], SEGC);
      unsigned s0 = (c == 0) ? 0u : (lbuf[j * SEGC] & 0x01FFFFFFu);
      lbuf[j * SEGC] = s0 | (c << 27);
    }
    __syncthreads();
    for (int j = t; j < NBKT; j += 256) {
      const uint4* __restrict__ s4 = (const uint4*)(lbuf + j * SEGC);
      uint4* __restrict__ d4 = (uint4*)(binbuf + ((size_t)j * NBIN + b) * SEGC);
      d4[0] = s4[0]; d4[1] = s4[1]; d4[2] = s4[2]; d4[3] = s4[3];
    }
    return;
  }

  // ---------------- tables ----------------
  float* sm = (float*)smem;
  int tb = b - NBIN;
  if (tb == 0) {
    for (int j = t; j < 1024; j += 256) {
      int isq = (j < 512);
      int h = (j >> 7) & 3, d = j & 127;
      const float* __restrict__ Wm = isq ? Wq : Wk;
      const float* __restrict__ am = isq ? att_i : att_j;
      float s = 0.f;
#pragma unroll
      for (int c = 0; c < NC; ++c) s = fmaf(am[h * NC + c], Wm[(h * NC + c) * D + d], s);
      sm[j] = s;
    }
    __syncthreads();
    for (int j = t; j < 1024; j += 256) {
      int r = j >> 6;
      int c2 = (j & 63) * 2;
      float a = 0.f, bb = 0.f;
      if (r < 8) { a = sm[r * 128 + c2]; bb = sm[r * 128 + c2 + 1]; }
      Wvh[(128 + r) * 64 + (j & 63)] = pack_bf16(a, bb);
    }
    if (t < 32) {  // a_et[ty][h] = wk_eff[h] . eemb[ty]
      int ty = t >> 2, hh = t & 3;
      const float* wrow = sm + 512 + hh * 128;
      const float* __restrict__ emb = eemb + ty * D;
      float s = 0.f;
#pragma unroll 8
      for (int d = 0; d < D; ++d) s = fmaf(wrow[d], emb[d], s);
      a_et[t] = s;
    }
  } else if (tb <= 8) {
    int ty = tb - 1;
    if (t < 128) sm[t] = eemb[ty * D + t];
    __syncthreads();
    if (t < 128) {
      const float4* __restrict__ wr = (const float4*)(Wv + (size_t)t * D);
      const float4* __restrict__ er = (const float4*)sm;
      float s = 0.f;
#pragma unroll
      for (int k = 0; k < 32; ++k) {
        float4 ww = wr[k], ee = er[k];
        s = fmaf(ww.x, ee.x, s); s = fmaf(ww.y, ee.y, s);
        s = fmaf(ww.z, ee.z, s); s = fmaf(ww.w, ee.w, s);
      }
      ev[ty * D + t] = s;
    }
  } else {
    int j0 = (tb - 9) * 1024;
    for (int j = j0 + t; j < j0 + 1024; j += 256)
      Wvh[j] = pack_bf16(Wv[2 * j], Wv[2 * j + 1]);
  }
}

// ====== MFMA xv (625 blocks) — verbatim ======
__global__ __launch_bounds__(256) void k_xv(
    const float* __restrict__ x, const int* __restrict__ node_type,
    const float* __restrict__ nemb, const unsigned* __restrict__ Wvh,
    unsigned* __restrict__ xvh, float* __restrict__ aq, float* __restrict__ ak) {
  int bb = blockIdx.x, t = threadIdx.x;
  int w = t >> 6, l = t & 63;
  int quad = l >> 4, col = l & 15;
  int n0w = bb * 64 + w * 16;  // 40000 = 625*64
  int node = n0w + col;
  int ntA = node_type[node];
  const float4* __restrict__ xr = (const float4*)(x + (size_t)node * D);
  const float4* __restrict__ nr = (const float4*)(nemb + (size_t)ntA * D);
  bf16x8 afr[4];
#pragma unroll
  for (int s = 0; s < 4; ++s) {
    const float4* p = xr + s * 8 + quad * 2;
    const float4* q4 = nr + s * 8 + quad * 2;
    afr[s] = to_bf16x8(f4add(p[0], q4[0]), f4add(p[1], q4[1]));
  }
  f32x4 acc[9];
#pragma unroll
  for (int ct = 0; ct < 9; ++ct) acc[ct] = (f32x4){0.f, 0.f, 0.f, 0.f};
#pragma unroll
  for (int ct = 0; ct < 9; ++ct) {
    const unsigned* __restrict__ brow = Wvh + (size_t)(ct * 16 + col) * 64;
#pragma unroll
    for (int s = 0; s < 4; ++s) {
      bf16x8 bfr = *(const bf16x8*)(brow + s * 16 + quad * 4);
      acc[ct] = __builtin_amdgcn_mfma_f32_16x16x32_bf16(afr[s], bfr, acc[ct], 0, 0, 0);
    }
  }
  int nodes[4];
#pragma unroll
  for (int r = 0; r < 4; ++r) nodes[r] = n0w + quad * 4 + r;
#pragma unroll
  for (int ct = 0; ct < 8; ++ct) {
#pragma unroll
    for (int r = 0; r < 4; ++r) {
      float val = acc[ct][r];
      float pv = __shfl_xor(val, 1);
      if (!(col & 1)) {
        xvh[nodes[r] * 64 + ct * 8 + (col >> 1)] = pack_bf16(val, pv);
      }
    }
  }
  if (col < 4) {
#pragma unroll
    for (int r = 0; r < 4; ++r) aq[nodes[r] * NH + col] = acc[8][r];
  } else if (col < 8) {
#pragma unroll
    for (int r = 0; r < 4; ++r) ak[nodes[r] * NH + (col - 4)] = acc[8][r];
  }
}

// ====== k_gb: 1250 blocks x 512 threads — one 32-node HALF-bucket per block
//        (b = bid>>1, hf = bid&1). Phase A: read the bucket's 500 segments,
//        filter records by half, build LDS CSR. Phase B: 8 waves x 4 nodes,
//        per-node edge-split gather (R3-verified inner loop). ======
__global__ __launch_bounds__(512) void k_gb(
    const unsigned* __restrict__ binbuf,
    const float* __restrict__ aq, const float* __restrict__ ak,
    const float* __restrict__ a_et, const unsigned* __restrict__ xvh,
    const float* __restrict__ ev, const float* __restrict__ bias,
    float* __restrict__ out) {
  __shared__ int lcnt[32];
  __shared__ unsigned csr[2048];
  int bid = blockIdx.x, t = threadIdx.x;
  int b = bid >> 1;   // bucket 0..624
  int hf = bid & 1;   // 32-node half
  if (t < 32) lcnt[t] = 0;
  __syncthreads();
  if (t < NBIN) {
    const unsigned* __restrict__ sp = binbuf + ((size_t)b * NBIN + t) * SEGC;
    uint4 a0 = *(const uint4*)sp;
    uint4 a1 = *(const uint4*)(sp + 4);
    uint4 a2 = *(const uint4*)(sp + 8);
    uint4 a3 = *(const uint4*)(sp + 12);
    unsigned rr[16] = {a0.x, a0.y, a0.z, a0.w, a1.x, a1.y, a1.z, a1.w,
                       a2.x, a2.y, a2.z, a2.w, a3.x, a3.y, a3.z, a3.w};
    int cnt = (int)(rr[0] >> 27);
    rr[0] &= 0x01FFFFFFu;
#pragma unroll
    for (int j = 0; j < SEGC; ++j) {
      if (j < cnt) {
        unsigned rec = rr[j];
        int loc = (int)(rec >> 19) & 63;
        if ((loc >> 5) == hf) {
          int r = atomicAdd(&lcnt[loc & 31], 1);
          if (r < 63) csr[((loc & 31) << 6) + r] = rec & 0x7FFFFu;  // src | et<<16
        }
      }
    }
  }
  __syncthreads();
  int w = t >> 6, l = t & 63;
  int g = l >> 3, q = l & 7;
  int h = q >> 1;
  const uint4* __restrict__ xv4 = (const uint4*)xvh;  // row = 16 uint4
  const float4* __restrict__ ep = (const float4*)(ev + g * D + 16 * q);
  float4 ea0 = ep[0], ea1 = ep[1], ea2 = ep[2], ea3 = ep[3];
#pragma unroll 1
  for (int j4 = 0; j4 < 4; ++j4) {
    int loc = (w << 2) + j4;              // 0..31 within the half
    int n = (b << 6) + (hf << 5) + loc;   // global node
    float aqh = aq[n * NH + h];
    int deg = min(lcnt[loc], 63);
    int m = deg + 1;  // + virtual self-loop at item index deg
    float acc[16];
#pragma unroll
    for (int k = 0; k < 16; ++k) acc[k] = 0.f;
    float ps[8];
#pragma unroll
    for (int k = 0; k < 8; ++k) ps[k] = 0.f;
    int iters = (m + 7) >> 3;
    int i = g;
    bool val = (i < m);
    unsigned rec = (val && i < deg) ? csr[(loc << 6) + i] : (unsigned)n;
    int src = (int)(rec & 0xFFFFu), etc = (int)(rec >> 16);
    float sA = ak[src * NH + h] + a_et[etc * NH + h];
    uint4 vb0 = xv4[src * 16 + 2 * q];
    uint4 vb1 = xv4[src * 16 + 2 * q + 1];
    for (int it = 0; it < iters; ++it) {
      int i2 = i + 8;
      bool v2 = (i2 < m);
      float sAn = 0.f; int etn = 0;
      uint4 vb0n = make_uint4(0, 0, 0, 0), vb1n = make_uint4(0, 0, 0, 0);
      if (it + 1 < iters) {
        unsigned rec2 = (v2 && i2 < deg) ? csr[(loc << 6) + i2] : (unsigned)n;
        int s2 = (int)(rec2 & 0xFFFFu);
        etn = (int)(rec2 >> 16);
        sAn = ak[s2 * NH + h] + a_et[etn * NH + h];
        vb0n = xv4[s2 * 16 + 2 * q];
        vb1n = xv4[s2 * 16 + 2 * q + 1];
      }
      float s = aqh + sA;
      s = (s > 0.f) ? s : NEG * s;
      float p = val ? __expf(s) : 0.f;
#pragma unroll
      for (int tt = 0; tt < 8; ++tt) ps[tt] += (etc == tt) ? p : 0.f;
      float f[16];
      f[0]  = __uint_as_float(vb0.x << 16); f[1]  = __uint_as_float(vb0.x & 0xFFFF0000u);
      f[2]  = __uint_as_float(vb0.y << 16); f[3]  = __uint_as_float(vb0.y & 0xFFFF0000u);
      f[4]  = __uint_as_float(vb0.z << 16); f[5]  = __uint_as_float(vb0.z & 0xFFFF0000u);
      f[6]  = __uint_as_float(vb0.w << 16); f[7]  = __uint_as_float(vb0.w & 0xFFFF0000u);
      f[8]  = __uint_as_float(vb1.x << 16); f[9]  = __uint_as_float(vb1.x & 0xFFFF0000u);
      f[10] = __uint_as_float(vb1.y << 16); f[11] = __uint_as_float(vb1.y & 0xFFFF0000u);
      f[12] = __uint_as_float(vb1.z << 16); f[13] = __uint_as_float(vb1.z & 0xFFFF0000u);
      f[14] = __uint_as_float(vb1.w << 16); f[15] = __uint_as_float(vb1.w & 0xFFFF0000u);
#pragma unroll
      for (int k = 0; k < 16; ++k) acc[k] = fmaf(p, f[k], acc[k]);
      i = i2; val = v2; sA = sAn; etc = etn; vb0 = vb0n; vb1 = vb1n;
    }
#pragma unroll
    for (int tt = 0; tt < 8; ++tt) {
      ps[tt] += __shfl_xor(ps[tt], 8);
      ps[tt] += __shfl_xor(ps[tt], 16);
      ps[tt] += __shfl_xor(ps[tt], 32);
    }
    float dsum = ((ps[0] + ps[1]) + (ps[2] + ps[3])) + ((ps[4] + ps[5]) + (ps[6] + ps[7]));
    float psg = ps[0];
#pragma unroll
    for (int tt = 1; tt < 8; ++tt) psg = (g == tt) ? ps[tt] : psg;
    acc[0]  = fmaf(psg, ea0.x, acc[0]);
    acc[1]  = fmaf(psg, ea0.y, acc[1]);
    acc[2]  = fmaf(psg, ea0.z, acc[2]);
    acc[3]  = fmaf(psg, ea0.w, acc[3]);
    acc[4]  = fmaf(psg, ea1.x, acc[4]);
    acc[5]  = fmaf(psg, ea1.y, acc[5]);
    acc[6]  = fmaf(psg, ea1.z, acc[6]);
    acc[7]  = fmaf(psg, ea1.w, acc[7]);
    acc[8]  = fmaf(psg, ea2.x, acc[8]);
    acc[9]  = fmaf(psg, ea2.y, acc[9]);
    acc[10] = fmaf(psg, ea2.z, acc[10]);
    acc[11] = fmaf(psg, ea2.w, acc[11]);
    acc[12] = fmaf(psg, ea3.x, acc[12]);
    acc[13] = fmaf(psg, ea3.y, acc[13]);
    acc[14] = fmaf(psg, ea3.z, acc[14]);
    acc[15] = fmaf(psg, ea3.w, acc[15]);
#pragma unroll
    for (int k = 0; k < 16; ++k) {
      acc[k] += __shfl_xor(acc[k], 8);
      acc[k] += __shfl_xor(acc[k], 16);
      acc[k] += __shfl_xor(acc[k], 32);
    }
    if (g == 0) {
      float inv = 1.f / (dsum + 1e-16f);
      const float4* __restrict__ b4 = (const float4*)(bias + 16 * q);
      float4* __restrict__ op = (float4*)(out + (size_t)n * D + 16 * q);
#pragma unroll
      for (int k4 = 0; k4 < 4; ++k4) {
        float4 bb = b4[k4];
        op[k4] = make_float4(acc[4 * k4 + 0] * inv + bb.x,
                             acc[4 * k4 + 1] * inv + bb.y,
                             acc[4 * k4 + 2] * inv + bb.z,
                             acc[4 * k4 + 3] * inv + bb.w);
      }
    }
  }
}

extern "C" void kernel_launch(void* const* d_in, const int* in_sizes, int n_in,
                              void* d_out, int out_size, void* d_ws, size_t ws_size,
                              hipStream_t stream) {
  const float* x      = (const float*)d_in[0];
  const int*   ei     = (const int*)d_in[1];
  const int*   ntype  = (const int*)d_in[2];
  const int*   etype  = (const int*)d_in[3];
  const float* Wq     = (const float*)d_in[4];
  const float* Wk     = (const float*)d_in[5];
  const float* Wv     = (const float*)d_in[6];
  const float* att_i  = (const float*)d_in[7];
  const float* att_j  = (const float*)d_in[8];
  const float* bias   = (const float*)d_in[9];
  const float* nemb   = (const float*)d_in[10];
  const float* eemb   = (const float*)d_in[11];
  float* out = (float*)d_out;

  float* ws     = (float*)d_ws;
  unsigned* xvh = (unsigned*)ws;               // NN*64 uints (bf16 pairs)
  float* aq     = ws + (size_t)NN * 64;        // NN*4
  float* ak     = aq + NN * NH;                // NN*4
  float* ev     = ak + NN * NH;                // 1024
  float* a_et   = ev + 1024;                   // 32
  unsigned* Wvh = (unsigned*)(a_et + 32);      // 144*64 = 9216 uints
  unsigned* binbuf = (unsigned*)(Wvh + 9216);  // NBKT*NBIN*SEGC = 5M uints = 20MB, 64B-aligned

  k_pb<<<dim3(NBIN + 17), dim3(256), 0, stream>>>(ei, etype, binbuf,
                                                  Wq, Wk, Wv, att_i, att_j, eemb,
                                                  ev, a_et, Wvh);
  k_xv<<<dim3(625), dim3(256), 0, stream>>>(x, ntype, nemb, Wvh, xvh, aq, ak);
  k_gb<<<dim3(2 * NBKT), dim3(512), 0, stream>>>(binbuf, aq, ak, a_et,
                                                 xvh, ev, bias, out);
}

// Round 12
// 169.199 us; speedup vs baseline: 1.2622x; 1.0147x over previous
//
#include <hip/hip_runtime.h>
#include <math.h>

#define NN 40000
#define NE 640000
#define D 128
#define NH 4
#define NC 32
#define NEG 0.2f

#define NBKT 1250     // buckets of 32 dst-nodes
#define NBIN 250      // binning blocks (2560 edges each); lambda=2.05/segment
#define SEGC 16       // records per (bucket,bin) segment = 64 B full line

typedef __attribute__((ext_vector_type(8))) short bf16x8;
typedef __attribute__((ext_vector_type(4))) float f32x4;

__device__ __forceinline__ unsigned pack_bf16(float a, float b) {
  unsigned ua = __float_as_uint(a), ub = __float_as_uint(b);
  ua = (ua + 0x7FFFu + ((ua >> 16) & 1u)) >> 16;
  ub = (ub + 0x7FFFu + ((ub >> 16) & 1u)) & 0xFFFF0000u;
  return ub | ua;
}

__device__ __forceinline__ bf16x8 to_bf16x8(float4 a, float4 b) {
  union { bf16x8 v; unsigned u[4]; } r;
  r.u[0] = pack_bf16(a.x, a.y);
  r.u[1] = pack_bf16(a.z, a.w);
  r.u[2] = pack_bf16(b.x, b.y);
  r.u[3] = pack_bf16(b.z, b.w);
  return r.v;
}

__device__ __forceinline__ float4 f4add(float4 a, float4 b) {
  return make_float4(a.x + b.x, a.y + b.y, a.z + b.z, a.w + b.w);
}

// ======= k_pb: b<250 -> LDS-staged edge binning into 32-node buckets via
//         TWO dst-half passes (slab 625x16 per pass), full-64B-line write-out
//         into [bucket][bin] layout, count in slot0 bits 27..31;
//         b>=250 -> weight tables (17 blocks). =======
__global__ __launch_bounds__(256) void k_pb(
    const int* __restrict__ ei, const int* __restrict__ etype,
    unsigned* __restrict__ binbuf,
    const float* __restrict__ Wq, const float* __restrict__ Wk,
    const float* __restrict__ Wv,
    const float* __restrict__ att_i, const float* __restrict__ att_j,
    const float* __restrict__ eemb,
    float* __restrict__ ev, float* __restrict__ a_et,
    unsigned* __restrict__ Wvh) {
  __shared__ unsigned smem[10640];  // bin: slab[10000] + hist[625] ; tables: sm[1024]f
  int b = blockIdx.x, t = threadIdx.x;

  if (b < NBIN) {
    unsigned* lbuf = smem;             // 625 segments x 16 (per pass)
    int* hist = (int*)(smem + 10000);  // 625
    int e0 = b * 2560;
#pragma unroll 1
    for (int pass = 0; pass < 2; ++pass) {
      int bk0 = pass * 625;
      for (int j = t; j < 625; j += 256) hist[j] = 0;
      __syncthreads();
#pragma unroll
      for (int k = 0; k < 10; ++k) {
        int e = e0 + k * 256 + t;
        int src = ei[e];
        int dst = ei[NE + e];
        int et  = etype[e];
        int bk = (dst >> 5) - bk0;
        if (bk >= 0 && bk < 625) {
          int r = atomicAdd(&hist[bk], 1);
          if (r < SEGC)
            lbuf[bk * SEGC + r] =
                (unsigned)src | ((unsigned)et << 16) | ((unsigned)(dst & 31) << 19);
        }
      }
      __syncthreads();
      // pack count into slot0 bits 27..31 (records use bits 0..23)
      for (int j = t; j < 625; j += 256) {
        unsigned c = (unsigned)min(hist[j], SEGC);
        unsigned s0 = (c == 0) ? 0u : (lbuf[j * SEGC] & 0x01FFFFFFu);
        lbuf[j * SEGC] = s0 | (c << 27);
      }
      __syncthreads();
      // write-out: one full 64-B segment per bucket, [bucket][bin] layout
      for (int j = t; j < 625; j += 256) {
        const uint4* __restrict__ s4 = (const uint4*)(lbuf + j * SEGC);
        uint4* __restrict__ d4 =
            (uint4*)(binbuf + ((size_t)(bk0 + j) * NBIN + b) * SEGC);
        d4[0] = s4[0]; d4[1] = s4[1]; d4[2] = s4[2]; d4[3] = s4[3];
      }
      __syncthreads();
    }
    return;
  }

  // ---------------- tables ----------------
  float* sm = (float*)smem;
  int tb = b - NBIN;
  if (tb == 0) {
    for (int j = t; j < 1024; j += 256) {
      int isq = (j < 512);
      int h = (j >> 7) & 3, d = j & 127;
      const float* __restrict__ Wm = isq ? Wq : Wk;
      const float* __restrict__ am = isq ? att_i : att_j;
      float s = 0.f;
#pragma unroll
      for (int c = 0; c < NC; ++c) s = fmaf(am[h * NC + c], Wm[(h * NC + c) * D + d], s);
      sm[j] = s;
    }
    __syncthreads();
    for (int j = t; j < 1024; j += 256) {
      int r = j >> 6;
      int c2 = (j & 63) * 2;
      float a = 0.f, bb = 0.f;
      if (r < 8) { a = sm[r * 128 + c2]; bb = sm[r * 128 + c2 + 1]; }
      Wvh[(128 + r) * 64 + (j & 63)] = pack_bf16(a, bb);
    }
    if (t < 32) {  // a_et[ty][h] = wk_eff[h] . eemb[ty]
      int ty = t >> 2, hh = t & 3;
      const float* wrow = sm + 512 + hh * 128;
      const float* __restrict__ emb = eemb + ty * D;
      float s = 0.f;
#pragma unroll 8
      for (int d = 0; d < D; ++d) s = fmaf(wrow[d], emb[d], s);
      a_et[t] = s;
    }
  } else if (tb <= 8) {
    int ty = tb - 1;
    if (t < 128) sm[t] = eemb[ty * D + t];
    __syncthreads();
    if (t < 128) {
      const float4* __restrict__ wr = (const float4*)(Wv + (size_t)t * D);
      const float4* __restrict__ er = (const float4*)sm;
      float s = 0.f;
#pragma unroll
      for (int k = 0; k < 32; ++k) {
        float4 ww = wr[k], ee = er[k];
        s = fmaf(ww.x, ee.x, s); s = fmaf(ww.y, ee.y, s);
        s = fmaf(ww.z, ee.z, s); s = fmaf(ww.w, ee.w, s);
      }
      ev[ty * D + t] = s;
    }
  } else {
    int j0 = (tb - 9) * 1024;
    for (int j = j0 + t; j < j0 + 1024; j += 256)
      Wvh[j] = pack_bf16(Wv[2 * j], Wv[2 * j + 1]);
  }
}

// ====== MFMA xv (625 blocks) — verbatim ======
__global__ __launch_bounds__(256) void k_xv(
    const float* __restrict__ x, const int* __restrict__ node_type,
    const float* __restrict__ nemb, const unsigned* __restrict__ Wvh,
    unsigned* __restrict__ xvh, float* __restrict__ aq, float* __restrict__ ak) {
  int bb = blockIdx.x, t = threadIdx.x;
  int w = t >> 6, l = t & 63;
  int quad = l >> 4, col = l & 15;
  int n0w = bb * 64 + w * 16;  // 40000 = 625*64
  int node = n0w + col;
  int ntA = node_type[node];
  const float4* __restrict__ xr = (const float4*)(x + (size_t)node * D);
  const float4* __restrict__ nr = (const float4*)(nemb + (size_t)ntA * D);
  bf16x8 afr[4];
#pragma unroll
  for (int s = 0; s < 4; ++s) {
    const float4* p = xr + s * 8 + quad * 2;
    const float4* q4 = nr + s * 8 + quad * 2;
    afr[s] = to_bf16x8(f4add(p[0], q4[0]), f4add(p[1], q4[1]));
  }
  f32x4 acc[9];
#pragma unroll
  for (int ct = 0; ct < 9; ++ct) acc[ct] = (f32x4){0.f, 0.f, 0.f, 0.f};
#pragma unroll
  for (int ct = 0; ct < 9; ++ct) {
    const unsigned* __restrict__ brow = Wvh + (size_t)(ct * 16 + col) * 64;
#pragma unroll
    for (int s = 0; s < 4; ++s) {
      bf16x8 bfr = *(const bf16x8*)(brow + s * 16 + quad * 4);
      acc[ct] = __builtin_amdgcn_mfma_f32_16x16x32_bf16(afr[s], bfr, acc[ct], 0, 0, 0);
    }
  }
  int nodes[4];
#pragma unroll
  for (int r = 0; r < 4; ++r) nodes[r] = n0w + quad * 4 + r;
#pragma unroll
  for (int ct = 0; ct < 8; ++ct) {
#pragma unroll
    for (int r = 0; r < 4; ++r) {
      float val = acc[ct][r];
      float pv = __shfl_xor(val, 1);
      if (!(col & 1)) {
        xvh[nodes[r] * 64 + ct * 8 + (col >> 1)] = pack_bf16(val, pv);
      }
    }
  }
  if (col < 4) {
#pragma unroll
    for (int r = 0; r < 4; ++r) aq[nodes[r] * NH + col] = acc[8][r];
  } else if (col < 8) {
#pragma unroll
    for (int r = 0; r < 4; ++r) ak[nodes[r] * NH + (col - 4)] = acc[8][r];
  }
}

// ====== k_gb: 1250 blocks x 512 threads — one 32-node bucket per block,
//        EXCLUSIVE bucket-contiguous segment reads (250 x 64 B = 16 KB).
//        Phase A: t<500 (2 threads/segment) -> LDS CSR (slot0 counts).
//        Phase B: 8 waves x 4 nodes, per-node edge-split gather. ======
__global__ __launch_bounds__(512) void k_gb(
    const unsigned* __restrict__ binbuf,
    const float* __restrict__ aq, const float* __restrict__ ak,
    const float* __restrict__ a_et, const unsigned* __restrict__ xvh,
    const float* __restrict__ ev, const float* __restrict__ bias,
    float* __restrict__ out) {
  __shared__ int lcnt[32];
  __shared__ unsigned csr[2048];
  int b = blockIdx.x, t = threadIdx.x;  // b = bucket 0..1249
  if (t < 32) lcnt[t] = 0;
  __syncthreads();
  if (t < 2 * NBIN) {
    int seg = t >> 1, half = t & 1;
    const unsigned* __restrict__ sp = binbuf + ((size_t)b * NBIN + seg) * SEGC;
    int cnt = (int)(sp[0] >> 27);
    int base = half * 8;
    if (cnt > base) {
      uint4 a0 = *(const uint4*)(sp + base);
      uint4 a1 = *(const uint4*)(sp + base + 4);
      unsigned rr[8] = {a0.x, a0.y, a0.z, a0.w, a1.x, a1.y, a1.z, a1.w};
      if (half == 0) rr[0] &= 0x01FFFFFFu;
      int jn = min(cnt - base, 8);
#pragma unroll
      for (int j = 0; j < 8; ++j) {
        if (j < jn) {
          unsigned rec = rr[j];
          int loc = (int)(rec >> 19) & 31;
          int r = atomicAdd(&lcnt[loc], 1);
          if (r < 63) csr[(loc << 6) + r] = rec & 0x7FFFFu;  // src | et<<16
        }
      }
    }
  }
  __syncthreads();
  int w = t >> 6, l = t & 63;
  int g = l >> 3, q = l & 7;
  int h = q >> 1;
  const uint4* __restrict__ xv4 = (const uint4*)xvh;  // row = 16 uint4
  const float4* __restrict__ ep = (const float4*)(ev + g * D + 16 * q);
  float4 ea0 = ep[0], ea1 = ep[1], ea2 = ep[2], ea3 = ep[3];
#pragma unroll 1
  for (int j4 = 0; j4 < 4; ++j4) {
    int loc = (w << 2) + j4;     // 0..31
    int n = (b << 5) + loc;      // global node
    float aqh = aq[n * NH + h];
    int deg = min(lcnt[loc], 63);
    int m = deg + 1;  // + virtual self-loop at item index deg
    float acc[16];
#pragma unroll
    for (int k = 0; k < 16; ++k) acc[k] = 0.f;
    float ps[8];
#pragma unroll
    for (int k = 0; k < 8; ++k) ps[k] = 0.f;
    int iters = (m + 7) >> 3;
    int i = g;
    bool val = (i < m);
    unsigned rec = (val && i < deg) ? csr[(loc << 6) + i] : (unsigned)n;
    int src = (int)(rec & 0xFFFFu), etc = (int)(rec >> 16);
    float sA = ak[src * NH + h] + a_et[etc * NH + h];
    uint4 vb0 = xv4[src * 16 + 2 * q];
    uint4 vb1 = xv4[src * 16 + 2 * q + 1];
    for (int it = 0; it < iters; ++it) {
      int i2 = i + 8;
      bool v2 = (i2 < m);
      float sAn = 0.f; int etn = 0;
      uint4 vb0n = make_uint4(0, 0, 0, 0), vb1n = make_uint4(0, 0, 0, 0);
      if (it + 1 < iters) {
        unsigned rec2 = (v2 && i2 < deg) ? csr[(loc << 6) + i2] : (unsigned)n;
        int s2 = (int)(rec2 & 0xFFFFu);
        etn = (int)(rec2 >> 16);
        sAn = ak[s2 * NH + h] + a_et[etn * NH + h];
        vb0n = xv4[s2 * 16 + 2 * q];
        vb1n = xv4[s2 * 16 + 2 * q + 1];
      }
      float s = aqh + sA;
      s = (s > 0.f) ? s : NEG * s;
      float p = val ? __expf(s) : 0.f;
#pragma unroll
      for (int tt = 0; tt < 8; ++tt) ps[tt] += (etc == tt) ? p : 0.f;
      float f[16];
      f[0]  = __uint_as_float(vb0.x << 16); f[1]  = __uint_as_float(vb0.x & 0xFFFF0000u);
      f[2]  = __uint_as_float(vb0.y << 16); f[3]  = __uint_as_float(vb0.y & 0xFFFF0000u);
      f[4]  = __uint_as_float(vb0.z << 16); f[5]  = __uint_as_float(vb0.z & 0xFFFF0000u);
      f[6]  = __uint_as_float(vb0.w << 16); f[7]  = __uint_as_float(vb0.w & 0xFFFF0000u);
      f[8]  = __uint_as_float(vb1.x << 16); f[9]  = __uint_as_float(vb1.x & 0xFFFF0000u);
      f[10] = __uint_as_float(vb1.y << 16); f[11] = __uint_as_float(vb1.y & 0xFFFF0000u);
      f[12] = __uint_as_float(vb1.z << 16); f[13] = __uint_as_float(vb1.z & 0xFFFF0000u);
      f[14] = __uint_as_float(vb1.w << 16); f[15] = __uint_as_float(vb1.w & 0xFFFF0000u);
#pragma unroll
      for (int k = 0; k < 16; ++k) acc[k] = fmaf(p, f[k], acc[k]);
      i = i2; val = v2; sA = sAn; etc = etn; vb0 = vb0n; vb1 = vb1n;
    }
#pragma unroll
    for (int tt = 0; tt < 8; ++tt) {
      ps[tt] += __shfl_xor(ps[tt], 8);
      ps[tt] += __shfl_xor(ps[tt], 16);
      ps[tt] += __shfl_xor(ps[tt], 32);
    }
    float dsum = ((ps[0] + ps[1]) + (ps[2] + ps[3])) + ((ps[4] + ps[5]) + (ps[6] + ps[7]));
    float psg = ps[0];
#pragma unroll
    for (int tt = 1; tt < 8; ++tt) psg = (g == tt) ? ps[tt] : psg;
    acc[0]  = fmaf(psg, ea0.x, acc[0]);
    acc[1]  = fmaf(psg, ea0.y, acc[1]);
    acc[2]  = fmaf(psg, ea0.z, acc[2]);
    acc[3]  = fmaf(psg, ea0.w, acc[3]);
    acc[4]  = fmaf(psg, ea1.x, acc[4]);
    acc[5]  = fmaf(psg, ea1.y, acc[5]);
    acc[6]  = fmaf(psg, ea1.z, acc[6]);
    acc[7]  = fmaf(psg, ea1.w, acc[7]);
    acc[8]  = fmaf(psg, ea2.x, acc[8]);
    acc[9]  = fmaf(psg, ea2.y, acc[9]);
    acc[10] = fmaf(psg, ea2.z, acc[10]);
    acc[11] = fmaf(psg, ea2.w, acc[11]);
    acc[12] = fmaf(psg, ea3.x, acc[12]);
    acc[13] = fmaf(psg, ea3.y, acc[13]);
    acc[14] = fmaf(psg, ea3.z, acc[14]);
    acc[15] = fmaf(psg, ea3.w, acc[15]);
#pragma unroll
    for (int k = 0; k < 16; ++k) {
      acc[k] += __shfl_xor(acc[k], 8);
      acc[k] += __shfl_xor(acc[k], 16);
      acc[k] += __shfl_xor(acc[k], 32);
    }
    if (g == 0) {
      float inv = 1.f / (dsum + 1e-16f);
      const float4* __restrict__ b4 = (const float4*)(bias + 16 * q);
      float4* __restrict__ op = (float4*)(out + (size_t)n * D + 16 * q);
#pragma unroll
      for (int k4 = 0; k4 < 4; ++k4) {
        float4 bb = b4[k4];
        op[k4] = make_float4(acc[4 * k4 + 0] * inv + bb.x,
                             acc[4 * k4 + 1] * inv + bb.y,
                             acc[4 * k4 + 2] * inv + bb.z,
                             acc[4 * k4 + 3] * inv + bb.w);
      }
    }
  }
}

extern "C" void kernel_launch(void* const* d_in, const int* in_sizes, int n_in,
                              void* d_out, int out_size, void* d_ws, size_t ws_size,
                              hipStream_t stream) {
  const float* x      = (const float*)d_in[0];
  const int*   ei     = (const int*)d_in[1];
  const int*   ntype  = (const int*)d_in[2];
  const int*   etype  = (const int*)d_in[3];
  const float* Wq     = (const float*)d_in[4];
  const float* Wk     = (const float*)d_in[5];
  const float* Wv     = (const float*)d_in[6];
  const float* att_i  = (const float*)d_in[7];
  const float* att_j  = (const float*)d_in[8];
  const float* bias   = (const float*)d_in[9];
  const float* nemb   = (const float*)d_in[10];
  const float* eemb   = (const float*)d_in[11];
  float* out = (float*)d_out;

  float* ws     = (float*)d_ws;
  unsigned* xvh = (unsigned*)ws;               // NN*64 uints (bf16 pairs)
  float* aq     = ws + (size_t)NN * 64;        // NN*4
  float* ak     = aq + NN * NH;                // NN*4
  float* ev     = ak + NN * NH;                // 1024
  float* a_et   = ev + 1024;                   // 32
  unsigned* Wvh = (unsigned*)(a_et + 32);      // 144*64 = 9216 uints
  unsigned* binbuf = (unsigned*)(Wvh + 9216);  // NBKT*NBIN*SEGC = 5M uints = 20MB, 64B-aligned

  k_pb<<<dim3(NBIN + 17), dim3(256), 0, stream>>>(ei, etype, binbuf,
                                                  Wq, Wk, Wv, att_i, att_j, eemb,
                                                  ev, a_et, Wvh);
  k_xv<<<dim3(625), dim3(256), 0, stream>>>(x, ntype, nemb, Wvh, xvh, aq, ak);
  k_gb<<<dim3(NBKT), dim3(512), 0, stream>>>(binbuf, aq, ak, a_et,
                                             xvh, ev, bias, out);
}

// Round 13
// 165.497 us; speedup vs baseline: 1.2904x; 1.0224x over previous
//
#include <hip/hip_runtime.h>
#include <math.h>

#define NN 40000
#define NE 640000
#define D 128
#define NH 4
#define NC 32
#define NEG 0.2f

#define NBKT 1250     // buckets of 32 dst-nodes
#define NBIN 250      // binning blocks (2560 edges each); lambda=2.05/segment
#define SEGC 16       // records per (bucket,bin) segment = 64 B full line

typedef __attribute__((ext_vector_type(8))) short bf16x8;
typedef __attribute__((ext_vector_type(4))) float f32x4;

__device__ __forceinline__ unsigned pack_bf16(float a, float b) {
  unsigned ua = __float_as_uint(a), ub = __float_as_uint(b);
  ua = (ua + 0x7FFFu + ((ua >> 16) & 1u)) >> 16;
  ub = (ub + 0x7FFFu + ((ub >> 16) & 1u)) & 0xFFFF0000u;
  return ub | ua;
}

__device__ __forceinline__ bf16x8 to_bf16x8(float4 a, float4 b) {
  union { bf16x8 v; unsigned u[4]; } r;
  r.u[0] = pack_bf16(a.x, a.y);
  r.u[1] = pack_bf16(a.z, a.w);
  r.u[2] = pack_bf16(b.x, b.y);
  r.u[3] = pack_bf16(b.z, b.w);
  return r.v;
}

__device__ __forceinline__ float4 f4add(float4 a, float4 b) {
  return make_float4(a.x + b.x, a.y + b.y, a.z + b.z, a.w + b.w);
}

// ======= k_pb (1024 threads): b<250 -> two-pass LDS-staged binning (16 waves
//         per block instead of 4 — same algorithm, 4x issue width);
//         b>=250 -> weight tables (17 blocks, guarded for 1024 thr). =======
__global__ __launch_bounds__(1024) void k_pb(
    const int* __restrict__ ei, const int* __restrict__ etype,
    unsigned* __restrict__ binbuf,
    const float* __restrict__ Wq, const float* __restrict__ Wk,
    const float* __restrict__ Wv,
    const float* __restrict__ att_i, const float* __restrict__ att_j,
    const float* __restrict__ eemb,
    float* __restrict__ ev, float* __restrict__ a_et,
    unsigned* __restrict__ Wvh) {
  __shared__ unsigned smem[10640];  // bin: slab[10000] + hist[625] ; tables: sm[1024]f
  int b = blockIdx.x, t = threadIdx.x;

  if (b < NBIN) {
    unsigned* lbuf = smem;             // 625 segments x 16 (per pass)
    int* hist = (int*)(smem + 10000);  // 625
    int e0 = b * 2560;
#pragma unroll 1
    for (int pass = 0; pass < 2; ++pass) {
      int bk0 = pass * 625;
      for (int j = t; j < 625; j += 1024) hist[j] = 0;
      __syncthreads();
#pragma unroll
      for (int k = 0; k < 3; ++k) {
        int ee = k * 1024 + t;
        if (ee < 2560) {
          int e = e0 + ee;
          int src = ei[e];
          int dst = ei[NE + e];
          int et  = etype[e];
          int bk = (dst >> 5) - bk0;
          if (bk >= 0 && bk < 625) {
            int r = atomicAdd(&hist[bk], 1);
            if (r < SEGC)
              lbuf[bk * SEGC + r] =
                  (unsigned)src | ((unsigned)et << 16) | ((unsigned)(dst & 31) << 19);
          }
        }
      }
      __syncthreads();
      // pack count into slot0 bits 27..31 (records use bits 0..23)
      for (int j = t; j < 625; j += 1024) {
        unsigned c = (unsigned)min(hist[j], SEGC);
        unsigned s0 = (c == 0) ? 0u : (lbuf[j * SEGC] & 0x01FFFFFFu);
        lbuf[j * SEGC] = s0 | (c << 27);
      }
      __syncthreads();
      // write-out: one full 64-B segment per bucket, [bucket][bin] layout
      for (int j = t; j < 625; j += 1024) {
        const uint4* __restrict__ s4 = (const uint4*)(lbuf + j * SEGC);
        uint4* __restrict__ d4 =
            (uint4*)(binbuf + ((size_t)(bk0 + j) * NBIN + b) * SEGC);
        d4[0] = s4[0]; d4[1] = s4[1]; d4[2] = s4[2]; d4[3] = s4[3];
      }
      __syncthreads();
    }
    return;
  }

  // ---------------- tables ----------------
  float* sm = (float*)smem;
  int tb = b - NBIN;
  if (tb == 0) {
    for (int j = t; j < 1024; j += 1024) {
      int isq = (j < 512);
      int h = (j >> 7) & 3, d = j & 127;
      const float* __restrict__ Wm = isq ? Wq : Wk;
      const float* __restrict__ am = isq ? att_i : att_j;
      float s = 0.f;
#pragma unroll
      for (int c = 0; c < NC; ++c) s = fmaf(am[h * NC + c], Wm[(h * NC + c) * D + d], s);
      sm[j] = s;
    }
    __syncthreads();
    for (int j = t; j < 1024; j += 1024) {
      int r = j >> 6;
      int c2 = (j & 63) * 2;
      float a = 0.f, bb = 0.f;
      if (r < 8) { a = sm[r * 128 + c2]; bb = sm[r * 128 + c2 + 1]; }
      Wvh[(128 + r) * 64 + (j & 63)] = pack_bf16(a, bb);
    }
    if (t < 32) {  // a_et[ty][h] = wk_eff[h] . eemb[ty]
      int ty = t >> 2, hh = t & 3;
      const float* wrow = sm + 512 + hh * 128;
      const float* __restrict__ emb = eemb + ty * D;
      float s = 0.f;
#pragma unroll 8
      for (int d = 0; d < D; ++d) s = fmaf(wrow[d], emb[d], s);
      a_et[t] = s;
    }
  } else if (tb <= 8) {
    int ty = tb - 1;
    if (t < 128) sm[t] = eemb[ty * D + t];
    __syncthreads();
    if (t < 128) {
      const float4* __restrict__ wr = (const float4*)(Wv + (size_t)t * D);
      const float4* __restrict__ er = (const float4*)sm;
      float s = 0.f;
#pragma unroll
      for (int k = 0; k < 32; ++k) {
        float4 ww = wr[k], ee = er[k];
        s = fmaf(ww.x, ee.x, s); s = fmaf(ww.y, ee.y, s);
        s = fmaf(ww.z, ee.z, s); s = fmaf(ww.w, ee.w, s);
      }
      ev[ty * D + t] = s;
    }
  } else {
    int j0 = (tb - 9) * 1024;
    for (int j = j0 + t; j < j0 + 1024; j += 1024)
      Wvh[j] = pack_bf16(Wv[2 * j], Wv[2 * j + 1]);
  }
}

// ====== MFMA xv: 2500 blocks x 64 threads, 16 nodes/block (1 wave).
//        Wave-level logic identical to the verified k_xv. ======
__global__ __launch_bounds__(64) void k_xv(
    const float* __restrict__ x, const int* __restrict__ node_type,
    const float* __restrict__ nemb, const unsigned* __restrict__ Wvh,
    unsigned* __restrict__ xvh, float* __restrict__ aq, float* __restrict__ ak) {
  int bb = blockIdx.x, l = threadIdx.x;  // l = lane 0..63
  int quad = l >> 4, col = l & 15;
  int n0w = bb * 16;  // 40000 = 2500*16
  int node = n0w + col;
  int ntA = node_type[node];
  const float4* __restrict__ xr = (const float4*)(x + (size_t)node * D);
  const float4* __restrict__ nr = (const float4*)(nemb + (size_t)ntA * D);
  bf16x8 afr[4];
#pragma unroll
  for (int s = 0; s < 4; ++s) {
    const float4* p = xr + s * 8 + quad * 2;
    const float4* q4 = nr + s * 8 + quad * 2;
    afr[s] = to_bf16x8(f4add(p[0], q4[0]), f4add(p[1], q4[1]));
  }
  f32x4 acc[9];
#pragma unroll
  for (int ct = 0; ct < 9; ++ct) acc[ct] = (f32x4){0.f, 0.f, 0.f, 0.f};
#pragma unroll
  for (int ct = 0; ct < 9; ++ct) {
    const unsigned* __restrict__ brow = Wvh + (size_t)(ct * 16 + col) * 64;
#pragma unroll
    for (int s = 0; s < 4; ++s) {
      bf16x8 bfr = *(const bf16x8*)(brow + s * 16 + quad * 4);
      acc[ct] = __builtin_amdgcn_mfma_f32_16x16x32_bf16(afr[s], bfr, acc[ct], 0, 0, 0);
    }
  }
  int nodes[4];
#pragma unroll
  for (int r = 0; r < 4; ++r) nodes[r] = n0w + quad * 4 + r;
#pragma unroll
  for (int ct = 0; ct < 8; ++ct) {
#pragma unroll
    for (int r = 0; r < 4; ++r) {
      float val = acc[ct][r];
      float pv = __shfl_xor(val, 1);
      if (!(col & 1)) {
        xvh[nodes[r] * 64 + ct * 8 + (col >> 1)] = pack_bf16(val, pv);
      }
    }
  }
  if (col < 4) {
#pragma unroll
    for (int r = 0; r < 4; ++r) aq[nodes[r] * NH + col] = acc[8][r];
  } else if (col < 8) {
#pragma unroll
    for (int r = 0; r < 4; ++r) ak[nodes[r] * NH + (col - 4)] = acc[8][r];
  }
}

// ====== k_gb: R12 verbatim — 1250 blocks x 512 threads, one 32-node bucket,
//        exclusive bucket-contiguous segment reads (250 x 64 B). ======
__global__ __launch_bounds__(512) void k_gb(
    const unsigned* __restrict__ binbuf,
    const float* __restrict__ aq, const float* __restrict__ ak,
    const float* __restrict__ a_et, const unsigned* __restrict__ xvh,
    const float* __restrict__ ev, const float* __restrict__ bias,
    float* __restrict__ out) {
  __shared__ int lcnt[32];
  __shared__ unsigned csr[2048];
  int b = blockIdx.x, t = threadIdx.x;  // b = bucket 0..1249
  if (t < 32) lcnt[t] = 0;
  __syncthreads();
  if (t < 2 * NBIN) {
    int seg = t >> 1, half = t & 1;
    const unsigned* __restrict__ sp = binbuf + ((size_t)b * NBIN + seg) * SEGC;
    int cnt = (int)(sp[0] >> 27);
    int base = half * 8;
    if (cnt > base) {
      uint4 a0 = *(const uint4*)(sp + base);
      uint4 a1 = *(const uint4*)(sp + base + 4);
      unsigned rr[8] = {a0.x, a0.y, a0.z, a0.w, a1.x, a1.y, a1.z, a1.w};
      if (half == 0) rr[0] &= 0x01FFFFFFu;
      int jn = min(cnt - base, 8);
#pragma unroll
      for (int j = 0; j < 8; ++j) {
        if (j < jn) {
          unsigned rec = rr[j];
          int loc = (int)(rec >> 19) & 31;
          int r = atomicAdd(&lcnt[loc], 1);
          if (r < 63) csr[(loc << 6) + r] = rec & 0x7FFFFu;  // src | et<<16
        }
      }
    }
  }
  __syncthreads();
  int w = t >> 6, l = t & 63;
  int g = l >> 3, q = l & 7;
  int h = q >> 1;
  const uint4* __restrict__ xv4 = (const uint4*)xvh;  // row = 16 uint4
  const float4* __restrict__ ep = (const float4*)(ev + g * D + 16 * q);
  float4 ea0 = ep[0], ea1 = ep[1], ea2 = ep[2], ea3 = ep[3];
#pragma unroll 1
  for (int j4 = 0; j4 < 4; ++j4) {
    int loc = (w << 2) + j4;     // 0..31
    int n = (b << 5) + loc;      // global node
    float aqh = aq[n * NH + h];
    int deg = min(lcnt[loc], 63);
    int m = deg + 1;  // + virtual self-loop at item index deg
    float acc[16];
#pragma unroll
    for (int k = 0; k < 16; ++k) acc[k] = 0.f;
    float ps[8];
#pragma unroll
    for (int k = 0; k < 8; ++k) ps[k] = 0.f;
    int iters = (m + 7) >> 3;
    int i = g;
    bool val = (i < m);
    unsigned rec = (val && i < deg) ? csr[(loc << 6) + i] : (unsigned)n;
    int src = (int)(rec & 0xFFFFu), etc = (int)(rec >> 16);
    float sA = ak[src * NH + h] + a_et[etc * NH + h];
    uint4 vb0 = xv4[src * 16 + 2 * q];
    uint4 vb1 = xv4[src * 16 + 2 * q + 1];
    for (int it = 0; it < iters; ++it) {
      int i2 = i + 8;
      bool v2 = (i2 < m);
      float sAn = 0.f; int etn = 0;
      uint4 vb0n = make_uint4(0, 0, 0, 0), vb1n = make_uint4(0, 0, 0, 0);
      if (it + 1 < iters) {
        unsigned rec2 = (v2 && i2 < deg) ? csr[(loc << 6) + i2] : (unsigned)n;
        int s2 = (int)(rec2 & 0xFFFFu);
        etn = (int)(rec2 >> 16);
        sAn = ak[s2 * NH + h] + a_et[etn * NH + h];
        vb0n = xv4[s2 * 16 + 2 * q];
        vb1n = xv4[s2 * 16 + 2 * q + 1];
      }
      float s = aqh + sA;
      s = (s > 0.f) ? s : NEG * s;
      float p = val ? __expf(s) : 0.f;
#pragma unroll
      for (int tt = 0; tt < 8; ++tt) ps[tt] += (etc == tt) ? p : 0.f;
      float f[16];
      f[0]  = __uint_as_float(vb0.x << 16); f[1]  = __uint_as_float(vb0.x & 0xFFFF0000u);
      f[2]  = __uint_as_float(vb0.y << 16); f[3]  = __uint_as_float(vb0.y & 0xFFFF0000u);
      f[4]  = __uint_as_float(vb0.z << 16); f[5]  = __uint_as_float(vb0.z & 0xFFFF0000u);
      f[6]  = __uint_as_float(vb0.w << 16); f[7]  = __uint_as_float(vb0.w & 0xFFFF0000u);
      f[8]  = __uint_as_float(vb1.x << 16); f[9]  = __uint_as_float(vb1.x & 0xFFFF0000u);
      f[10] = __uint_as_float(vb1.y << 16); f[11] = __uint_as_float(vb1.y & 0xFFFF0000u);
      f[12] = __uint_as_float(vb1.z << 16); f[13] = __uint_as_float(vb1.z & 0xFFFF0000u);
      f[14] = __uint_as_float(vb1.w << 16); f[15] = __uint_as_float(vb1.w & 0xFFFF0000u);
#pragma unroll
      for (int k = 0; k < 16; ++k) acc[k] = fmaf(p, f[k], acc[k]);
      i = i2; val = v2; sA = sAn; etc = etn; vb0 = vb0n; vb1 = vb1n;
    }
#pragma unroll
    for (int tt = 0; tt < 8; ++tt) {
      ps[tt] += __shfl_xor(ps[tt], 8);
      ps[tt] += __shfl_xor(ps[tt], 16);
      ps[tt] += __shfl_xor(ps[tt], 32);
    }
    float dsum = ((ps[0] + ps[1]) + (ps[2] + ps[3])) + ((ps[4] + ps[5]) + (ps[6] + ps[7]));
    float psg = ps[0];
#pragma unroll
    for (int tt = 1; tt < 8; ++tt) psg = (g == tt) ? ps[tt] : psg;
    acc[0]  = fmaf(psg, ea0.x, acc[0]);
    acc[1]  = fmaf(psg, ea0.y, acc[1]);
    acc[2]  = fmaf(psg, ea0.z, acc[2]);
    acc[3]  = fmaf(psg, ea0.w, acc[3]);
    acc[4]  = fmaf(psg, ea1.x, acc[4]);
    acc[5]  = fmaf(psg, ea1.y, acc[5]);
    acc[6]  = fmaf(psg, ea1.z, acc[6]);
    acc[7]  = fmaf(psg, ea1.w, acc[7]);
    acc[8]  = fmaf(psg, ea2.x, acc[8]);
    acc[9]  = fmaf(psg, ea2.y, acc[9]);
    acc[10] = fmaf(psg, ea2.z, acc[10]);
    acc[11] = fmaf(psg, ea2.w, acc[11]);
    acc[12] = fmaf(psg, ea3.x, acc[12]);
    acc[13] = fmaf(psg, ea3.y, acc[13]);
    acc[14] = fmaf(psg, ea3.z, acc[14]);
    acc[15] = fmaf(psg, ea3.w, acc[15]);
#pragma unroll
    for (int k = 0; k < 16; ++k) {
      acc[k] += __shfl_xor(acc[k], 8);
      acc[k] += __shfl_xor(acc[k], 16);
      acc[k] += __shfl_xor(acc[k], 32);
    }
    if (g == 0) {
      float inv = 1.f / (dsum + 1e-16f);
      const float4* __restrict__ b4 = (const float4*)(bias + 16 * q);
      float4* __restrict__ op = (float4*)(out + (size_t)n * D + 16 * q);
#pragma unroll
      for (int k4 = 0; k4 < 4; ++k4) {
        float4 bb = b4[k4];
        op[k4] = make_float4(acc[4 * k4 + 0] * inv + bb.x,
                             acc[4 * k4 + 1] * inv + bb.y,
                             acc[4 * k4 + 2] * inv + bb.z,
                             acc[4 * k4 + 3] * inv + bb.w);
      }
    }
  }
}

extern "C" void kernel_launch(void* const* d_in, const int* in_sizes, int n_in,
                              void* d_out, int out_size, void* d_ws, size_t ws_size,
                              hipStream_t stream) {
  const float* x      = (const float*)d_in[0];
  const int*   ei     = (const int*)d_in[1];
  const int*   ntype  = (const int*)d_in[2];
  const int*   etype  = (const int*)d_in[3];
  const float* Wq     = (const float*)d_in[4];
  const float* Wk     = (const float*)d_in[5];
  const float* Wv     = (const float*)d_in[6];
  const float* att_i  = (const float*)d_in[7];
  const float* att_j  = (const float*)d_in[8];
  const float* bias   = (const float*)d_in[9];
  const float* nemb   = (const float*)d_in[10];
  const float* eemb   = (const float*)d_in[11];
  float* out = (float*)d_out;

  float* ws     = (float*)d_ws;
  unsigned* xvh = (unsigned*)ws;               // NN*64 uints (bf16 pairs)
  float* aq     = ws + (size_t)NN * 64;        // NN*4
  float* ak     = aq + NN * NH;                // NN*4
  float* ev     = ak + NN * NH;                // 1024
  float* a_et   = ev + 1024;                   // 32
  unsigned* Wvh = (unsigned*)(a_et + 32);      // 144*64 = 9216 uints
  unsigned* binbuf = (unsigned*)(Wvh + 9216);  // NBKT*NBIN*SEGC = 5M uints = 20MB, 64B-aligned

  k_pb<<<dim3(NBIN + 17), dim3(1024), 0, stream>>>(ei, etype, binbuf,
                                                   Wq, Wk, Wv, att_i, att_j, eemb,
                                                   ev, a_et, Wvh);
  k_xv<<<dim3(2500), dim3(64), 0, stream>>>(x, ntype, nemb, Wvh, xvh, aq, ak);
  k_gb<<<dim3(NBKT), dim3(512), 0, stream>>>(binbuf, aq, ak, a_et,
                                             xvh, ev, bias, out);
}